// Round 1
// baseline (5728.353 us; speedup 1.0000x reference)
//
#include <hip/hip_runtime.h>
#include <hip/hip_bf16.h>

// Problem constants
// x: [2, 2048, 1024] f32; mask: [2, 2048, 2048] f32; W_qkv: [1024, 3072] f32
// W_out: [1024, 1024] f32; b_out: [1024] f32; out: [2, 2048, 1024] f32
#define BATCH 2
#define SEQ   2048
#define DIM   1024
#define HEADS 16
#define DH    64
#define N_QKV 3072
#define M_TOT 4096   // BATCH*SEQ
#define SCALE 0.125f // DH^-0.5
#define EPS   1e-10f

// ---------------------------------------------------------------------------
// GEMM 1: qkv = x @ W_qkv, scattered into q/k/v buffers laid out [b, h, l, dh]
// BM=BN=64, BK=16, 256 threads, 4x4 outputs per thread.
// ---------------------------------------------------------------------------
__global__ __launch_bounds__(256) void gemm_qkv(const float* __restrict__ A,
                                                const float* __restrict__ Bw,
                                                float* __restrict__ q,
                                                float* __restrict__ k,
                                                float* __restrict__ v) {
    __shared__ float As[16][64];
    __shared__ float Bs[16][64];
    const int m0 = blockIdx.y * 64;
    const int n0 = blockIdx.x * 64;
    const int t  = threadIdx.x;
    const int tx = t & 15;   // 0..15  -> 4 output cols
    const int ty = t >> 4;   // 0..15  -> 4 output rows
    float acc[4][4] = {};

    for (int k0 = 0; k0 < DIM; k0 += 16) {
        #pragma unroll
        for (int idx = t; idx < 64 * 16; idx += 256) {
            int mm = idx >> 4, kc = idx & 15;
            As[kc][mm] = A[(long)(m0 + mm) * DIM + k0 + kc];
        }
        #pragma unroll
        for (int idx = t; idx < 16 * 64; idx += 256) {
            int kr = idx >> 6, nn = idx & 63;
            Bs[kr][nn] = Bw[(long)(k0 + kr) * N_QKV + n0 + nn];
        }
        __syncthreads();
        #pragma unroll
        for (int kc = 0; kc < 16; ++kc) {
            float ra[4], rb[4];
            #pragma unroll
            for (int i = 0; i < 4; ++i) ra[i] = As[kc][ty * 4 + i];
            #pragma unroll
            for (int j = 0; j < 4; ++j) rb[j] = Bs[kc][tx * 4 + j];
            #pragma unroll
            for (int i = 0; i < 4; ++i)
                #pragma unroll
                for (int j = 0; j < 4; ++j) acc[i][j] += ra[i] * rb[j];
        }
        __syncthreads();
    }

    #pragma unroll
    for (int i = 0; i < 4; ++i) {
        const int m  = m0 + ty * 4 + i;
        const int bb = m >> 11;       // m / 2048
        const int li = m & 2047;
        #pragma unroll
        for (int j = 0; j < 4; ++j) {
            const int n     = n0 + tx * 4 + j;
            const int which = n >> 10;        // 0:q 1:k 2:v
            const int rem   = n & 1023;
            const int head  = rem >> 6;
            const int d     = rem & 63;
            float* dst = (which == 0) ? q : (which == 1) ? k : v;
            dst[((long)(bb * HEADS + head) * SEQ + li) * DH + d] = acc[i][j];
        }
    }
}

// ---------------------------------------------------------------------------
// Attention: one wave (64 lanes) per (b, h, query-row i).
// w_j = p_j * m_j / (sum(p*m) + eps*Z), p_j = exp(s_j - max), Z = sum(p).
// Exactly equivalent to softmax -> *mask -> renormalize(+eps).
// ---------------------------------------------------------------------------
__global__ __launch_bounds__(64) void attn_kernel(const float* __restrict__ q,
                                                  const float* __restrict__ k,
                                                  const float* __restrict__ v,
                                                  const float* __restrict__ mask,
                                                  float* __restrict__ z) {
    const int i  = blockIdx.x;
    const int h  = blockIdx.y;
    const int bb = blockIdx.z;
    const int t  = threadIdx.x;

    __shared__ float qs[DH];
    __shared__ float ss[SEQ];

    const long base = (long)(bb * HEADS + h) * SEQ * DH;

    qs[t] = q[base + (long)i * DH + t] * SCALE;
    __syncthreads();

    // scores: lane t handles keys t, t+64, ...
    for (int j = t; j < SEQ; j += 64) {
        const float* kr = k + base + (long)j * DH;
        float sum = 0.f;
        #pragma unroll
        for (int d = 0; d < DH; d += 4) {
            float4 k4 = *reinterpret_cast<const float4*>(kr + d);
            sum += qs[d] * k4.x + qs[d + 1] * k4.y + qs[d + 2] * k4.z + qs[d + 3] * k4.w;
        }
        ss[j] = sum;
    }
    __syncthreads();

    // wave max over all 2048 scores
    float lmax = -INFINITY;
    for (int j = t; j < SEQ; j += 64) lmax = fmaxf(lmax, ss[j]);
    #pragma unroll
    for (int off = 32; off > 0; off >>= 1) lmax = fmaxf(lmax, __shfl_xor(lmax, off, 64));

    // exp, mask, partial sums
    const float* mrow = mask + ((long)bb * SEQ + i) * SEQ;
    float lZ = 0.f, lZm = 0.f;
    for (int j = t; j < SEQ; j += 64) {
        float p  = __expf(ss[j] - lmax);
        lZ += p;
        float pm = p * mrow[j];
        ss[j] = pm;
        lZm += pm;
    }
    #pragma unroll
    for (int off = 32; off > 0; off >>= 1) {
        lZ  += __shfl_xor(lZ,  off, 64);
        lZm += __shfl_xor(lZm, off, 64);
    }
    __syncthreads();

    const float inv = 1.f / (lZm + EPS * lZ);

    // z[d] = sum_j w_j * V[j, d]; lane t = d (coalesced V reads)
    float acc = 0.f;
    const float* vp = v + base + t;
    #pragma unroll 8
    for (int j = 0; j < SEQ; ++j) {
        acc += ss[j] * vp[(long)j * DH];
    }
    z[((long)bb * SEQ + i) * DIM + h * DH + t] = acc * inv;
}

// ---------------------------------------------------------------------------
// GEMM 2: out = z @ W_out + b_out. M=4096, K=1024, N=1024.
// ---------------------------------------------------------------------------
__global__ __launch_bounds__(256) void gemm_out(const float* __restrict__ A,
                                                const float* __restrict__ Bw,
                                                const float* __restrict__ bias,
                                                float* __restrict__ C) {
    __shared__ float As[16][64];
    __shared__ float Bs[16][64];
    const int m0 = blockIdx.y * 64;
    const int n0 = blockIdx.x * 64;
    const int t  = threadIdx.x;
    const int tx = t & 15;
    const int ty = t >> 4;
    float acc[4][4] = {};

    for (int k0 = 0; k0 < DIM; k0 += 16) {
        #pragma unroll
        for (int idx = t; idx < 64 * 16; idx += 256) {
            int mm = idx >> 4, kc = idx & 15;
            As[kc][mm] = A[(long)(m0 + mm) * DIM + k0 + kc];
        }
        #pragma unroll
        for (int idx = t; idx < 16 * 64; idx += 256) {
            int kr = idx >> 6, nn = idx & 63;
            Bs[kr][nn] = Bw[(long)(k0 + kr) * DIM + n0 + nn];
        }
        __syncthreads();
        #pragma unroll
        for (int kc = 0; kc < 16; ++kc) {
            float ra[4], rb[4];
            #pragma unroll
            for (int i = 0; i < 4; ++i) ra[i] = As[kc][ty * 4 + i];
            #pragma unroll
            for (int j = 0; j < 4; ++j) rb[j] = Bs[kc][tx * 4 + j];
            #pragma unroll
            for (int i = 0; i < 4; ++i)
                #pragma unroll
                for (int j = 0; j < 4; ++j) acc[i][j] += ra[i] * rb[j];
        }
        __syncthreads();
    }

    #pragma unroll
    for (int i = 0; i < 4; ++i) {
        const int m = m0 + ty * 4 + i;
        #pragma unroll
        for (int j = 0; j < 4; ++j) {
            const int n = n0 + tx * 4 + j;
            C[(long)m * DIM + n] = acc[i][j] + bias[n];
        }
    }
}

// ---------------------------------------------------------------------------
extern "C" void kernel_launch(void* const* d_in, const int* in_sizes, int n_in,
                              void* d_out, int out_size, void* d_ws, size_t ws_size,
                              hipStream_t stream) {
    const float* x     = (const float*)d_in[0];
    const float* mask  = (const float*)d_in[1];
    const float* W_qkv = (const float*)d_in[2];
    const float* W_out = (const float*)d_in[3];
    const float* b_out = (const float*)d_in[4];
    float* out = (float*)d_out;

    float* ws = (float*)d_ws;
    const long per = (long)BATCH * HEADS * SEQ * DH; // 4,194,304 floats
    float* q = ws;
    float* k = q + per;
    float* v = k + per;
    float* z = v + per; // [b, l, inner] = 4,194,304 floats

    // qkv projection + scatter to [b,h,l,dh]
    gemm_qkv<<<dim3(N_QKV / 64, M_TOT / 64), 256, 0, stream>>>(x, W_qkv, q, k, v);

    // attention, one wave per (b, h, i)
    attn_kernel<<<dim3(SEQ, HEADS, BATCH), 64, 0, stream>>>(q, k, v, mask, z);

    // output projection + bias
    gemm_out<<<dim3(DIM / 64, M_TOT / 64), 256, 0, stream>>>(z, W_out, b_out, out);
}

// Round 2
// 948.360 us; speedup vs baseline: 6.0403x; 6.0403x over previous
//
#include <hip/hip_runtime.h>
#include <hip/hip_bf16.h>

// x: [2, 2048, 1024] f32; mask: [2, 2048, 2048] f32; W_qkv: [1024, 3072] f32
// W_out: [1024, 1024] f32; b_out: [1024] f32; out: [2, 2048, 1024] f32
#define BATCH 2
#define SEQ   2048
#define DIM   1024
#define HEADS 16
#define DH    64
#define N_QKV 3072
#define M_TOT 4096
#define SCALE 0.125f
#define EPS   1e-10f

typedef __attribute__((ext_vector_type(8))) short short8;
typedef __attribute__((ext_vector_type(4))) float f32x4;

static __device__ __forceinline__ unsigned short f2bf(float f) {
    __hip_bfloat16 h = __float2bfloat16(f);
    return *reinterpret_cast<unsigned short*>(&h);
}

// ---------------------------------------------------------------------------
// GEMM 1: qkv = x @ W_qkv. Epilogue: q (pre-scaled) + k as bf16 [b,h,l,dh],
// v as bf16 TRANSPOSED [b,h,dh,l] so attention B-fragments are contiguous.
// ---------------------------------------------------------------------------
__global__ __launch_bounds__(256) void gemm_qkv(const float* __restrict__ A,
                                                const float* __restrict__ Bw,
                                                unsigned short* __restrict__ qb,
                                                unsigned short* __restrict__ kb,
                                                unsigned short* __restrict__ vtb) {
    __shared__ float As[16][64];
    __shared__ float Bs[16][64];
    const int m0 = blockIdx.y * 64;
    const int n0 = blockIdx.x * 64;
    const int t  = threadIdx.x;
    const int tx = t & 15;
    const int ty = t >> 4;
    float acc[4][4] = {};

    for (int k0 = 0; k0 < DIM; k0 += 16) {
        #pragma unroll
        for (int idx = t; idx < 64 * 16; idx += 256) {
            int mm = idx >> 4, kc = idx & 15;
            As[kc][mm] = A[(long)(m0 + mm) * DIM + k0 + kc];
        }
        #pragma unroll
        for (int idx = t; idx < 16 * 64; idx += 256) {
            int kr = idx >> 6, nn = idx & 63;
            Bs[kr][nn] = Bw[(long)(k0 + kr) * N_QKV + n0 + nn];
        }
        __syncthreads();
        #pragma unroll
        for (int kc = 0; kc < 16; ++kc) {
            float ra[4], rb[4];
            #pragma unroll
            for (int i = 0; i < 4; ++i) ra[i] = As[kc][ty * 4 + i];
            #pragma unroll
            for (int j = 0; j < 4; ++j) rb[j] = Bs[kc][tx * 4 + j];
            #pragma unroll
            for (int i = 0; i < 4; ++i)
                #pragma unroll
                for (int j = 0; j < 4; ++j) acc[i][j] += ra[i] * rb[j];
        }
        __syncthreads();
    }

    #pragma unroll
    for (int i = 0; i < 4; ++i) {
        const int m  = m0 + ty * 4 + i;
        const int bb = m >> 11;
        const int li = m & 2047;
        #pragma unroll
        for (int j = 0; j < 4; ++j) {
            const int n     = n0 + tx * 4 + j;
            const int which = n >> 10;
            const int rem   = n & 1023;
            const int head  = rem >> 6;
            const int d     = rem & 63;
            const int bh    = bb * HEADS + head;
            float val = acc[i][j];
            if (which == 0) {
                qb[((long)bh * SEQ + li) * DH + d] = f2bf(val * SCALE);
            } else if (which == 1) {
                kb[((long)bh * SEQ + li) * DH + d] = f2bf(val);
            } else {
                vtb[((long)bh * DH + d) * SEQ + li] = f2bf(val);
            }
        }
    }
}

// ---------------------------------------------------------------------------
// MFMA flash attention. Block = 4 waves; wave w owns 16 q rows; K-tile = 64.
// S frags: A=Q[16x32], B=K^T (both load as rows of [l,dh], per m92 symmetry).
// P (=exp(s-m)*mask, bf16) round-trips LDS (C/D layout -> A layout, m120).
// Online stats: m (row max), Z=sum p, Zm=sum p*mask; out = O/(Zm + eps*Z).
// ---------------------------------------------------------------------------
__global__ __launch_bounds__(256) void attn_mfma(const unsigned short* __restrict__ qb,
                                                 const unsigned short* __restrict__ kb,
                                                 const unsigned short* __restrict__ vtb,
                                                 const float* __restrict__ mask,
                                                 float* __restrict__ z) {
    const int qt   = blockIdx.x;            // 0..31
    const int h    = blockIdx.y;
    const int bb   = blockIdx.z;
    const int bh   = bb * HEADS + h;
    const int wave = threadIdx.x >> 6;
    const int lane = threadIdx.x & 63;
    const int l16  = lane & 15;
    const int g    = lane >> 4;             // quad group 0..3

    const int i0 = qt * 64 + wave * 16;     // first q row of this wave

    __shared__ unsigned short p_lds[4][16][72];   // wave-private, +8 pad

    // Q fragments (k = d: 0..31, 32..63)
    const unsigned short* qptr = qb + ((long)bh * SEQ + i0 + l16) * DH + g * 8;
    const short8 q0 = *reinterpret_cast<const short8*>(qptr);
    const short8 q1 = *reinterpret_cast<const short8*>(qptr + 32);

    f32x4 o[4] = {};                         // O accum: 4 d-tiles x 4 rows
    float mrow[4], Zp[4], Zpm[4];
    #pragma unroll
    for (int r = 0; r < 4; ++r) { mrow[r] = -INFINITY; Zp[r] = 0.f; Zpm[r] = 0.f; }

    const float* maskb = mask + (long)bb * SEQ * SEQ;

    for (int j0 = 0; j0 < SEQ; j0 += 64) {
        // ---- S = Q K^T, 4 column tiles of 16 ----
        f32x4 s[4];
        #pragma unroll
        for (int nt = 0; nt < 4; ++nt) {
            const unsigned short* kp = kb + ((long)bh * SEQ + j0 + nt * 16 + l16) * DH + g * 8;
            short8 k0 = *reinterpret_cast<const short8*>(kp);
            short8 k1 = *reinterpret_cast<const short8*>(kp + 32);
            f32x4 acc = {0.f, 0.f, 0.f, 0.f};
            acc = __builtin_amdgcn_mfma_f32_16x16x32_bf16(q0, k0, acc, 0, 0, 0);
            acc = __builtin_amdgcn_mfma_f32_16x16x32_bf16(q1, k1, acc, 0, 0, 0);
            s[nt] = acc;
        }

        // ---- per-row tile max (reduce across the 16 lanes of each quad) ----
        float tmax[4];
        #pragma unroll
        for (int r = 0; r < 4; ++r)
            tmax[r] = fmaxf(fmaxf(s[0][r], s[1][r]), fmaxf(s[2][r], s[3][r]));
        #pragma unroll
        for (int off = 1; off < 16; off <<= 1)
            #pragma unroll
            for (int r = 0; r < 4; ++r)
                tmax[r] = fmaxf(tmax[r], __shfl_xor(tmax[r], off, 64));

        // ---- online rescale ----
        float alpha[4];
        #pragma unroll
        for (int r = 0; r < 4; ++r) {
            float mn  = fmaxf(mrow[r], tmax[r]);
            alpha[r]  = __expf(mrow[r] - mn);
            mrow[r]   = mn;
            Zp[r]    *= alpha[r];
            Zpm[r]   *= alpha[r];
        }
        #pragma unroll
        for (int nt = 0; nt < 4; ++nt)
            #pragma unroll
            for (int r = 0; r < 4; ++r)
                o[nt][r] *= alpha[r];

        // ---- p = exp(s-m), apply mask, stage P tile (bf16) in LDS ----
        #pragma unroll
        for (int nt = 0; nt < 4; ++nt) {
            #pragma unroll
            for (int r = 0; r < 4; ++r) {
                const int row = g * 4 + r;          // C/D layout row
                const int col = nt * 16 + l16;      // C/D layout col
                float p  = __expf(s[nt][r] - mrow[r]);
                Zp[r]   += p;
                float mv = maskb[(long)(i0 + row) * SEQ + j0 + col];
                float pm = p * mv;
                Zpm[r]  += pm;
                p_lds[wave][row][col] = f2bf(pm);
            }
        }
        __syncthreads();

        // ---- O += P V : A = P (from LDS, A-layout), B = V^T rows ----
        #pragma unroll
        for (int jc = 0; jc < 2; ++jc) {
            const short8 pf = *reinterpret_cast<const short8*>(&p_lds[wave][l16][jc * 32 + g * 8]);
            #pragma unroll
            for (int nt = 0; nt < 4; ++nt) {
                const unsigned short* vp =
                    vtb + ((long)bh * DH + nt * 16 + l16) * SEQ + j0 + jc * 32 + g * 8;
                short8 vf = *reinterpret_cast<const short8*>(vp);
                o[nt] = __builtin_amdgcn_mfma_f32_16x16x32_bf16(pf, vf, o[nt], 0, 0, 0);
            }
        }
        __syncthreads();
    }

    // ---- finalize: reduce Z/Zm across the 16 lanes, normalize, store ----
    #pragma unroll
    for (int off = 1; off < 16; off <<= 1)
        #pragma unroll
        for (int r = 0; r < 4; ++r) {
            Zp[r]  += __shfl_xor(Zp[r],  off, 64);
            Zpm[r] += __shfl_xor(Zpm[r], off, 64);
        }
    float inv[4];
    #pragma unroll
    for (int r = 0; r < 4; ++r) inv[r] = 1.f / (Zpm[r] + EPS * Zp[r]);

    #pragma unroll
    for (int nt = 0; nt < 4; ++nt)
        #pragma unroll
        for (int r = 0; r < 4; ++r) {
            const int row = i0 + g * 4 + r;
            z[((long)bb * SEQ + row) * DIM + h * DH + nt * 16 + l16] = o[nt][r] * inv[r];
        }
}

// ---------------------------------------------------------------------------
// GEMM 2: out = z @ W_out + b_out (fp32)
// ---------------------------------------------------------------------------
__global__ __launch_bounds__(256) void gemm_out(const float* __restrict__ A,
                                                const float* __restrict__ Bw,
                                                const float* __restrict__ bias,
                                                float* __restrict__ C) {
    __shared__ float As[16][64];
    __shared__ float Bs[16][64];
    const int m0 = blockIdx.y * 64;
    const int n0 = blockIdx.x * 64;
    const int t  = threadIdx.x;
    const int tx = t & 15;
    const int ty = t >> 4;
    float acc[4][4] = {};

    for (int k0 = 0; k0 < DIM; k0 += 16) {
        #pragma unroll
        for (int idx = t; idx < 64 * 16; idx += 256) {
            int mm = idx >> 4, kc = idx & 15;
            As[kc][mm] = A[(long)(m0 + mm) * DIM + k0 + kc];
        }
        #pragma unroll
        for (int idx = t; idx < 16 * 64; idx += 256) {
            int kr = idx >> 6, nn = idx & 63;
            Bs[kr][nn] = Bw[(long)(k0 + kr) * DIM + n0 + nn];
        }
        __syncthreads();
        #pragma unroll
        for (int kc = 0; kc < 16; ++kc) {
            float ra[4], rb[4];
            #pragma unroll
            for (int i = 0; i < 4; ++i) ra[i] = As[kc][ty * 4 + i];
            #pragma unroll
            for (int j = 0; j < 4; ++j) rb[j] = Bs[kc][tx * 4 + j];
            #pragma unroll
            for (int i = 0; i < 4; ++i)
                #pragma unroll
                for (int j = 0; j < 4; ++j) acc[i][j] += ra[i] * rb[j];
        }
        __syncthreads();
    }

    #pragma unroll
    for (int i = 0; i < 4; ++i) {
        const int m = m0 + ty * 4 + i;
        #pragma unroll
        for (int j = 0; j < 4; ++j) {
            const int n = n0 + tx * 4 + j;
            C[(long)m * DIM + n] = acc[i][j] + bias[n];
        }
    }
}

// ---------------------------------------------------------------------------
extern "C" void kernel_launch(void* const* d_in, const int* in_sizes, int n_in,
                              void* d_out, int out_size, void* d_ws, size_t ws_size,
                              hipStream_t stream) {
    const float* x     = (const float*)d_in[0];
    const float* mask  = (const float*)d_in[1];
    const float* W_qkv = (const float*)d_in[2];
    const float* W_out = (const float*)d_in[3];
    const float* b_out = (const float*)d_in[4];
    float* out = (float*)d_out;

    const long per = (long)BATCH * HEADS * SEQ * DH;   // 4,194,304 elements

    float* z = (float*)d_ws;                           // [b, l, 1024] fp32
    unsigned short* qb  = (unsigned short*)(z + per);  // bf16 [b,h,l,dh]
    unsigned short* kb  = qb + per;                    // bf16 [b,h,l,dh]
    unsigned short* vtb = kb + per;                    // bf16 [b,h,dh,l]

    gemm_qkv<<<dim3(N_QKV / 64, M_TOT / 64), 256, 0, stream>>>(x, W_qkv, qb, kb, vtb);

    attn_mfma<<<dim3(SEQ / 64, HEADS, BATCH), 256, 0, stream>>>(qb, kb, vtb, mask, z);

    gemm_out<<<dim3(DIM / 64, M_TOT / 64), 256, 0, stream>>>(z, W_out, b_out, out);
}

// Round 3
// 495.952 us; speedup vs baseline: 11.5502x; 1.9122x over previous
//
#include <hip/hip_runtime.h>
#include <hip/hip_bf16.h>

// x: [2, 2048, 1024] f32; mask: [2, 2048, 2048] f32; W_qkv: [1024, 3072] f32
// W_out: [1024, 1024] f32; b_out: [1024] f32; out: [2, 2048, 1024] f32
#define BATCH 2
#define SEQ   2048
#define DIM   1024
#define HEADS 16
#define DH    64
#define N_QKV 3072
#define M_TOT 4096
#define SCALE 0.125f
#define EPS   1e-10f

typedef __attribute__((ext_vector_type(8))) short short8;
typedef __attribute__((ext_vector_type(4))) float f32x4;

static __device__ __forceinline__ unsigned short f2bf(float f) {
    __hip_bfloat16 h = __float2bfloat16(f);
    return *reinterpret_cast<unsigned short*>(&h);
}
static __device__ __forceinline__ float bf2f(unsigned short u) {
    unsigned int x = ((unsigned int)u) << 16;
    return __builtin_bit_cast(float, x);
}
// async global->LDS, 16B per lane; LDS dest = wave-uniform base + lane*16
static __device__ __forceinline__ void glds16(const void* g, void* l) {
    __builtin_amdgcn_global_load_lds((const __attribute__((address_space(1))) void*)g,
                                     (__attribute__((address_space(3))) void*)l,
                                     16, 0, 0);
}

// ---------------------------------------------------------------------------
// Pre-pass: split fp32 -> bf16 hi + bf16 lo (residual). n4 = elems/4.
// ---------------------------------------------------------------------------
__global__ __launch_bounds__(256) void convert_hilo(const float* __restrict__ s,
                                                    unsigned short* __restrict__ h,
                                                    unsigned short* __restrict__ l) {
    const int i = blockIdx.x * 256 + threadIdx.x;
    float4 v = reinterpret_cast<const float4*>(s)[i];
    ushort4 hv, lv;
    hv.x = f2bf(v.x); lv.x = f2bf(v.x - bf2f(hv.x));
    hv.y = f2bf(v.y); lv.y = f2bf(v.y - bf2f(hv.y));
    hv.z = f2bf(v.z); lv.z = f2bf(v.z - bf2f(hv.z));
    hv.w = f2bf(v.w); lv.w = f2bf(v.w - bf2f(hv.w));
    reinterpret_cast<ushort4*>(h)[i] = hv;
    reinterpret_cast<ushort4*>(l)[i] = lv;
}

// ---------------------------------------------------------------------------
// Pre-pass: W [rows(k)][cols(n)] fp32 -> WT hi/lo bf16 [n][k]
// ---------------------------------------------------------------------------
__global__ __launch_bounds__(256) void transpose_hilo(const float* __restrict__ src,
                                                      unsigned short* __restrict__ th,
                                                      unsigned short* __restrict__ tl,
                                                      int rows, int cols) {
    __shared__ float tile[32][33];
    const int c0 = blockIdx.x * 32, r0 = blockIdx.y * 32;
    const int tx = threadIdx.x & 31, ty = threadIdx.x >> 5;
    #pragma unroll
    for (int i = ty; i < 32; i += 8)
        tile[i][tx] = src[(long)(r0 + i) * cols + c0 + tx];
    __syncthreads();
    #pragma unroll
    for (int i = ty; i < 32; i += 8) {
        float v = tile[tx][i];                  // = src[r0+tx][c0+i]
        unsigned short hv = f2bf(v);
        th[(long)(c0 + i) * rows + r0 + tx] = hv;
        tl[(long)(c0 + i) * rows + r0 + tx] = f2bf(v - bf2f(hv));
    }
}

// ---------------------------------------------------------------------------
// bf16x3 MFMA GEMM: C = (Ah+Al)(Bh+Bl) ~= AhBh + AhBl + AlBh, fp32 acc.
// A hi/lo: [M][1024] bf16; B hi/lo: [N][1024] bf16 (pre-transposed).
// 128x128 tile, BK=32, 4 waves -> 64x64 each. EPI 0: qkv scatter; 1: out+bias.
// ---------------------------------------------------------------------------
template <int EPI>
__global__ __launch_bounds__(256) void gemm_bf16x3(
    const unsigned short* __restrict__ Ahg, const unsigned short* __restrict__ Alg,
    const unsigned short* __restrict__ Bhg, const unsigned short* __restrict__ Blg,
    unsigned short* __restrict__ qb, unsigned short* __restrict__ kb,
    unsigned short* __restrict__ vtb,
    const float* __restrict__ bias, float* __restrict__ out) {
    __shared__ __align__(16) unsigned short Ah_s[128 * 32];
    __shared__ __align__(16) unsigned short Al_s[128 * 32];
    __shared__ __align__(16) unsigned short Bh_s[128 * 32];
    __shared__ __align__(16) unsigned short Bl_s[128 * 32];

    const int n0   = blockIdx.x * 128;
    const int m0   = blockIdx.y * 128;
    const int wave = threadIdx.x >> 6;
    const int lane = threadIdx.x & 63;
    const int l16  = lane & 15;
    const int g    = lane >> 4;
    const int wm   = wave & 1;
    const int wn   = wave >> 1;

    const int srow   = lane >> 2;          // staging: row within 16-row chunk
    const int schunk = (lane & 3) * 8;     // staging: k offset (elems)

    f32x4 acc[4][4] = {};

    for (int k0 = 0; k0 < DIM; k0 += 32) {
        // ---- stage A/B hi+lo tiles: each wave 8 glds (16 rows x 32 k each) ----
        #pragma unroll
        for (int i = 0; i < 2; ++i) {
            const int row = wave * 32 + i * 16;                       // uniform
            const long ga = (long)(m0 + row + srow) * DIM + k0 + schunk;
            const long gb = (long)(n0 + row + srow) * DIM + k0 + schunk;
            glds16(Ahg + ga, &Ah_s[row * 32]);
            glds16(Alg + ga, &Al_s[row * 32]);
            glds16(Bhg + gb, &Bh_s[row * 32]);
            glds16(Blg + gb, &Bl_s[row * 32]);
        }
        __syncthreads();

        short8 ah[4], al[4];
        #pragma unroll
        for (int mt = 0; mt < 4; ++mt) {
            const int r = (wm * 64 + mt * 16 + l16) * 32 + g * 8;
            ah[mt] = *reinterpret_cast<const short8*>(&Ah_s[r]);
            al[mt] = *reinterpret_cast<const short8*>(&Al_s[r]);
        }
        #pragma unroll
        for (int nt = 0; nt < 4; ++nt) {
            const int r = (wn * 64 + nt * 16 + l16) * 32 + g * 8;
            const short8 bh = *reinterpret_cast<const short8*>(&Bh_s[r]);
            const short8 bl = *reinterpret_cast<const short8*>(&Bl_s[r]);
            #pragma unroll
            for (int mt = 0; mt < 4; ++mt) {
                acc[mt][nt] = __builtin_amdgcn_mfma_f32_16x16x32_bf16(ah[mt], bh, acc[mt][nt], 0, 0, 0);
                acc[mt][nt] = __builtin_amdgcn_mfma_f32_16x16x32_bf16(ah[mt], bl, acc[mt][nt], 0, 0, 0);
                acc[mt][nt] = __builtin_amdgcn_mfma_f32_16x16x32_bf16(al[mt], bh, acc[mt][nt], 0, 0, 0);
            }
        }
        __syncthreads();
    }

    if constexpr (EPI == 0) {
        // scatter into q (pre-scaled), k [b,h,l,dh] and v^T [b,h,dh,l], bf16
        #pragma unroll
        for (int nt = 0; nt < 4; ++nt) {
            const int n     = n0 + wn * 64 + nt * 16 + l16;
            const int which = n >> 10;
            const int rem   = n & 1023;
            const int head  = rem >> 6;
            const int d     = rem & 63;
            #pragma unroll
            for (int mt = 0; mt < 4; ++mt) {
                #pragma unroll
                for (int r = 0; r < 4; ++r) {
                    const int m  = m0 + wm * 64 + mt * 16 + g * 4 + r;
                    const int bb = m >> 11;
                    const int li = m & 2047;
                    const int bh_i = bb * HEADS + head;
                    const float val = acc[mt][nt][r];
                    if (which == 0)
                        qb[((long)bh_i * SEQ + li) * DH + d] = f2bf(val * SCALE);
                    else if (which == 1)
                        kb[((long)bh_i * SEQ + li) * DH + d] = f2bf(val);
                    else
                        vtb[((long)bh_i * DH + d) * SEQ + li] = f2bf(val);
                }
            }
        }
    } else {
        #pragma unroll
        for (int nt = 0; nt < 4; ++nt) {
            const int n  = n0 + wn * 64 + nt * 16 + l16;
            const float bv = bias[n];
            #pragma unroll
            for (int mt = 0; mt < 4; ++mt) {
                #pragma unroll
                for (int r = 0; r < 4; ++r) {
                    const int m = m0 + wm * 64 + mt * 16 + g * 4 + r;
                    out[(long)m * DIM + n] = acc[mt][nt][r] + bv;
                }
            }
        }
    }
}

// ---------------------------------------------------------------------------
// MFMA flash attention (round-2 verified). Epilogue now emits z as bf16 hi/lo.
// ---------------------------------------------------------------------------
__global__ __launch_bounds__(256) void attn_mfma(const unsigned short* __restrict__ qb,
                                                 const unsigned short* __restrict__ kb,
                                                 const unsigned short* __restrict__ vtb,
                                                 const float* __restrict__ mask,
                                                 unsigned short* __restrict__ zh,
                                                 unsigned short* __restrict__ zl) {
    const int qt   = blockIdx.x;
    const int h    = blockIdx.y;
    const int bb   = blockIdx.z;
    const int bh   = bb * HEADS + h;
    const int wave = threadIdx.x >> 6;
    const int lane = threadIdx.x & 63;
    const int l16  = lane & 15;
    const int g    = lane >> 4;

    const int i0 = qt * 64 + wave * 16;

    __shared__ unsigned short p_lds[4][16][72];

    const unsigned short* qptr = qb + ((long)bh * SEQ + i0 + l16) * DH + g * 8;
    const short8 q0 = *reinterpret_cast<const short8*>(qptr);
    const short8 q1 = *reinterpret_cast<const short8*>(qptr + 32);

    f32x4 o[4] = {};
    float mrow[4], Zp[4], Zpm[4];
    #pragma unroll
    for (int r = 0; r < 4; ++r) { mrow[r] = -INFINITY; Zp[r] = 0.f; Zpm[r] = 0.f; }

    const float* maskb = mask + (long)bb * SEQ * SEQ;

    for (int j0 = 0; j0 < SEQ; j0 += 64) {
        f32x4 s[4];
        #pragma unroll
        for (int nt = 0; nt < 4; ++nt) {
            const unsigned short* kp = kb + ((long)bh * SEQ + j0 + nt * 16 + l16) * DH + g * 8;
            short8 k0 = *reinterpret_cast<const short8*>(kp);
            short8 k1 = *reinterpret_cast<const short8*>(kp + 32);
            f32x4 acc = {0.f, 0.f, 0.f, 0.f};
            acc = __builtin_amdgcn_mfma_f32_16x16x32_bf16(q0, k0, acc, 0, 0, 0);
            acc = __builtin_amdgcn_mfma_f32_16x16x32_bf16(q1, k1, acc, 0, 0, 0);
            s[nt] = acc;
        }

        float tmax[4];
        #pragma unroll
        for (int r = 0; r < 4; ++r)
            tmax[r] = fmaxf(fmaxf(s[0][r], s[1][r]), fmaxf(s[2][r], s[3][r]));
        #pragma unroll
        for (int off = 1; off < 16; off <<= 1)
            #pragma unroll
            for (int r = 0; r < 4; ++r)
                tmax[r] = fmaxf(tmax[r], __shfl_xor(tmax[r], off, 64));

        float alpha[4];
        #pragma unroll
        for (int r = 0; r < 4; ++r) {
            float mn  = fmaxf(mrow[r], tmax[r]);
            alpha[r]  = __expf(mrow[r] - mn);
            mrow[r]   = mn;
            Zp[r]    *= alpha[r];
            Zpm[r]   *= alpha[r];
        }
        #pragma unroll
        for (int nt = 0; nt < 4; ++nt)
            #pragma unroll
            for (int r = 0; r < 4; ++r)
                o[nt][r] *= alpha[r];

        #pragma unroll
        for (int nt = 0; nt < 4; ++nt) {
            #pragma unroll
            for (int r = 0; r < 4; ++r) {
                const int row = g * 4 + r;
                const int col = nt * 16 + l16;
                float p  = __expf(s[nt][r] - mrow[r]);
                Zp[r]   += p;
                float mv = maskb[(long)(i0 + row) * SEQ + j0 + col];
                float pm = p * mv;
                Zpm[r]  += pm;
                p_lds[wave][row][col] = f2bf(pm);
            }
        }
        __syncthreads();

        #pragma unroll
        for (int jc = 0; jc < 2; ++jc) {
            const short8 pf = *reinterpret_cast<const short8*>(&p_lds[wave][l16][jc * 32 + g * 8]);
            #pragma unroll
            for (int nt = 0; nt < 4; ++nt) {
                const unsigned short* vp =
                    vtb + ((long)bh * DH + nt * 16 + l16) * SEQ + j0 + jc * 32 + g * 8;
                short8 vf = *reinterpret_cast<const short8*>(vp);
                o[nt] = __builtin_amdgcn_mfma_f32_16x16x32_bf16(pf, vf, o[nt], 0, 0, 0);
            }
        }
        __syncthreads();
    }

    #pragma unroll
    for (int off = 1; off < 16; off <<= 1)
        #pragma unroll
        for (int r = 0; r < 4; ++r) {
            Zp[r]  += __shfl_xor(Zp[r],  off, 64);
            Zpm[r] += __shfl_xor(Zpm[r], off, 64);
        }
    float inv[4];
    #pragma unroll
    for (int r = 0; r < 4; ++r) inv[r] = 1.f / (Zpm[r] + EPS * Zp[r]);

    #pragma unroll
    for (int nt = 0; nt < 4; ++nt)
        #pragma unroll
        for (int r = 0; r < 4; ++r) {
            const int row = i0 + g * 4 + r;
            const long idx = ((long)bb * SEQ + row) * DIM + h * DH + nt * 16 + l16;
            const float val = o[nt][r] * inv[r];
            const unsigned short hv = f2bf(val);
            zh[idx] = hv;
            zl[idx] = f2bf(val - bf2f(hv));
        }
}

// ---------------------------------------------------------------------------
extern "C" void kernel_launch(void* const* d_in, const int* in_sizes, int n_in,
                              void* d_out, int out_size, void* d_ws, size_t ws_size,
                              hipStream_t stream) {
    const float* x     = (const float*)d_in[0];
    const float* mask  = (const float*)d_in[1];
    const float* W_qkv = (const float*)d_in[2];
    const float* W_out = (const float*)d_in[3];
    const float* b_out = (const float*)d_in[4];
    float* out = (float*)d_out;

    unsigned short* ws = (unsigned short*)d_ws;
    unsigned short* xh   = ws;                 // 4M  (reused as zh after gemm1)
    unsigned short* xl   = xh   + 4194304;     // 4M  (reused as zl)
    unsigned short* WqTh = xl   + 4194304;     // 3M
    unsigned short* WqTl = WqTh + 3145728;     // 3M
    unsigned short* WoTh = WqTl + 3145728;     // 1M
    unsigned short* WoTl = WoTh + 1048576;     // 1M
    unsigned short* qb   = WoTl + 1048576;     // 4M
    unsigned short* kb   = qb   + 4194304;     // 4M
    unsigned short* vtb  = kb   + 4194304;     // 4M  -> total 56 MB
    unsigned short* zzh  = xh;
    unsigned short* zzl  = xl;

    convert_hilo<<<4096, 256, 0, stream>>>(x, xh, xl);
    transpose_hilo<<<dim3(96, 32), 256, 0, stream>>>(W_qkv, WqTh, WqTl, 1024, 3072);
    transpose_hilo<<<dim3(32, 32), 256, 0, stream>>>(W_out, WoTh, WoTl, 1024, 1024);

    gemm_bf16x3<0><<<dim3(24, 32), 256, 0, stream>>>(xh, xl, WqTh, WqTl,
                                                     qb, kb, vtb, nullptr, nullptr);

    attn_mfma<<<dim3(SEQ / 64, HEADS, BATCH), 256, 0, stream>>>(qb, kb, vtb, mask, zzh, zzl);

    gemm_bf16x3<1><<<dim3(8, 32), 256, 0, stream>>>(zzh, zzl, WoTh, WoTl,
                                                    nullptr, nullptr, nullptr, b_out, out);
}